// Round 5
// baseline (785.015 us; speedup 1.0000x reference)
//
#include <hip/hip_runtime.h>
#include <hip/hip_bf16.h>

// GapModel: per_row[n] = (1/||ps_n||^2) * sum_m w[s_n,m] * (ps_n . sp[s_n,m])^2
// energy[t] = sum_{n: sid[n]==t} per_row[n]
//
// R5: barrier-free direct-to-fragment GEMM. The 16x16x32 MFMA A/B fragment
// layout (row = lane&15, k = (lane>>4)*8 + j) is loadable straight from
// row-major global memory: B (bf16, L2-resident) via one b128/frag, A (fp32)
// via two b128/frag + in-register cvt, with ||ps||^2 fused. No LDS staging,
// no K-loop barriers -> no vmcnt(0) drains (R2/R3 stall) ; full static unroll,
// no dynamically-indexed register arrays -> no scratch spills (R4 bug:
// WRITE_SIZE 131 MB was spill traffic).

constexpr int kNEnv     = 100000;
constexpr int kDPS      = 512;
constexpr int kNSpecies = 4;
constexpr int kNSupport = 256;
constexpr int kCap      = 32768;

constexpr int BN = 64;           // envs per block
constexpr int KC = kDPS / 32;    // 16 K-chunks of 32

typedef __attribute__((ext_vector_type(8))) short short8;
typedef __attribute__((ext_vector_type(4))) float f32x4;

__device__ __forceinline__ short8 pack_bf16x8(const float4& a, const float4& b) {
  union { short8 v; __hip_bfloat162 h[4]; } u;
  u.h[0] = __float22bfloat162_rn({a.x, a.y});
  u.h[1] = __float22bfloat162_rn({a.z, a.w});
  u.h[2] = __float22bfloat162_rn({b.x, b.y});
  u.h[3] = __float22bfloat162_rn({b.z, b.w});
  return u.v;
}

// ---------------- single-pass species bucket scatter ----------------
__global__ void scatter_kernel(const int* __restrict__ species, const int* __restrict__ sid,
                               int* __restrict__ cnt, int* __restrict__ perm,
                               int* __restrict__ sidp) {
  __shared__ int lcnt[kNSpecies];
  __shared__ int lbase[kNSpecies];
  int t = threadIdx.x;
  if (t < kNSpecies) lcnt[t] = 0;
  __syncthreads();
  int i = blockIdx.x * 256 + t;
  bool v = i < kNEnv;
  int s = 0, r = 0, g = 0;
  if (v) { s = species[i]; r = atomicAdd(&lcnt[s], 1); g = sid[i]; }
  __syncthreads();
  if (t < kNSpecies) lbase[t] = lcnt[t] ? atomicAdd(&cnt[t], lcnt[t]) : 0;
  __syncthreads();
  if (v) {
    int d = s * kCap + lbase[s] + r;
    perm[d] = i;
    sidp[d] = g;
  }
}

// ---------------- sp fp32 -> bf16 (2 MB; leaves sp_bf hot in L2) ----------
__global__ __launch_bounds__(256) void convert_sp_kernel(
    const float* __restrict__ sp, short* __restrict__ sp_bf) {
  size_t g = ((size_t)blockIdx.x * 256 + threadIdx.x) * 8;
  float4 x = *(const float4*)(sp + g);
  float4 y = *(const float4*)(sp + g + 4);
  *(short8*)(sp_bf + g) = pack_bf16x8(x, y);
}

// ---------------- barrier-free fused GEMM + norm + epilogue ----------------
// 256 threads = 4 waves; wave wv owns 64 env x m-slice [wv*64, wv*64+64).
// Per K-chunk (32): 4 A frags (fp32 2xb128 -> cvt) + 4 B frags (1xb128) + 16 MFMA.
__global__ __launch_bounds__(256, 2) void gap_gemm_kernel(
    const float* __restrict__ ps, const short* __restrict__ sp_bf,
    const float* __restrict__ w, const int* __restrict__ cnt,
    const int* __restrict__ perm, const int* __restrict__ sidp,
    float* __restrict__ energy) {
  const int s     = blockIdx.y;
  const int count = min(cnt[s], kCap);
  const int tile0 = blockIdx.x * BN;
  if (tile0 >= count) return;

  __shared__ int   prm[BN];
  __shared__ float red[4][BN];
  __shared__ float sqs[BN];

  const int tid  = threadIdx.x;
  const int wv   = tid >> 6;
  const int lane = tid & 63;
  const int l15  = lane & 15;
  const int lq   = lane >> 4;

  if (tid < BN) {
    int ge = tile0 + tid;
    prm[tid] = perm[s * kCap + (ge < count ? ge : count - 1)];
  }
  __syncthreads();

  // A frag base: env row fi*16+l15, k start lq*8 (imm offsets cover all kc)
  const float* aptr[4];
  #pragma unroll
  for (int fi = 0; fi < 4; ++fi)
    aptr[fi] = ps + (size_t)prm[fi * 16 + l15] * kDPS + lq * 8;
  // B frag base: m row wv*64+fj*16+l15
  const short* bptr[4];
  #pragma unroll
  for (int fj = 0; fj < 4; ++fj)
    bptr[fj] = sp_bf + ((size_t)s * kNSupport + wv * 64 + fj * 16 + l15) * kDPS + lq * 8;

  f32x4 acc[4][4];
  #pragma unroll
  for (int i = 0; i < 4; ++i)
    #pragma unroll
    for (int j = 0; j < 4; ++j) acc[i][j] = (f32x4)0.f;

  float sq[4] = {0.f, 0.f, 0.f, 0.f};

  #pragma unroll
  for (int kc = 0; kc < KC; ++kc) {
    float4 a0[4], a1[4];
    uint4  bl[4];
    #pragma unroll
    for (int fi = 0; fi < 4; ++fi) {
      a0[fi] = *(const float4*)(aptr[fi] + kc * 32);
      a1[fi] = *(const float4*)(aptr[fi] + kc * 32 + 4);
    }
    #pragma unroll
    for (int fj = 0; fj < 4; ++fj)
      bl[fj] = *(const uint4*)(bptr[fj] + kc * 32);

    short8 af[4], bf4[4];
    #pragma unroll
    for (int fi = 0; fi < 4; ++fi) {
      const float4 x = a0[fi], y = a1[fi];
      sq[fi] += x.x * x.x + x.y * x.y + x.z * x.z + x.w * x.w
              + y.x * y.x + y.y * y.y + y.z * y.z + y.w * y.w;
      af[fi] = pack_bf16x8(x, y);
      union { uint4 u; short8 v; } cvt; cvt.u = bl[fi];
      bf4[fi] = cvt.v;
    }
    #pragma unroll
    for (int fi = 0; fi < 4; ++fi)
      #pragma unroll
      for (int fj = 0; fj < 4; ++fj)
        acc[fi][fj] = __builtin_amdgcn_mfma_f32_16x16x32_bf16(af[fi], bf4[fj], acc[fi][fj], 0, 0, 0);
  }

  // ||ps||^2: env e = fi*16+l15 elements live in the 4 lq lanes -> xor-reduce
  #pragma unroll
  for (int fi = 0; fi < 4; ++fi) {
    sq[fi] += __shfl_xor(sq[fi], 16, 64);
    sq[fi] += __shfl_xor(sq[fi], 32, 64);
    if (wv == 0 && lq == 0) sqs[fi * 16 + l15] = sq[fi];
  }

  // epilogue: contrib = sum_m w_m * C^2 ; C/D: col(m)=l15, row(env)=lq*4+reg
  const float* w_s = w + s * kNSupport;
  float wgt[4];
  #pragma unroll
  for (int fj = 0; fj < 4; ++fj) wgt[fj] = w_s[wv * 64 + fj * 16 + l15];

  #pragma unroll
  for (int fi = 0; fi < 4; ++fi) {
    #pragma unroll
    for (int rr = 0; rr < 4; ++rr) {
      float p = 0.f;
      #pragma unroll
      for (int fj = 0; fj < 4; ++fj) {
        float cv = acc[fi][fj][rr];
        p += cv * cv * wgt[fj];
      }
      p += __shfl_xor(p, 1, 64);
      p += __shfl_xor(p, 2, 64);
      p += __shfl_xor(p, 4, 64);
      p += __shfl_xor(p, 8, 64);
      if (l15 == 0) red[wv][fi * 16 + lq * 4 + rr] = p;
    }
  }
  __syncthreads();
  if (tid < BN) {
    float v = red[0][tid] + red[1][tid] + red[2][tid] + red[3][tid];
    int g = tile0 + tid;
    if (g < count)
      atomicAdd(&energy[sidp[s * kCap + g]], v / sqs[tid]);
  }
}

extern "C" void kernel_launch(void* const* d_in, const int* in_sizes, int n_in,
                              void* d_out, int out_size, void* d_ws, size_t ws_size,
                              hipStream_t stream) {
  const float* ps      = (const float*)d_in[0];
  const float* sp      = (const float*)d_in[1];
  const float* w       = (const float*)d_in[2];
  const int*   species = (const int*)d_in[3];
  const int*   sid     = (const int*)d_in[4];
  float* energy = (float*)d_out;

  char* wsb = (char*)d_ws;
  size_t off = 0;
  int* cnt  = (int*)(wsb + off); off += 256;
  int* perm = (int*)(wsb + off); off += (size_t)kNSpecies * kCap * 4;
  int* sidp = (int*)(wsb + off); off += (size_t)kNSpecies * kCap * 4;
  short* sp_bf = (short*)(wsb + off);

  hipMemsetAsync(cnt, 0, 16, stream);
  hipMemsetAsync(energy, 0, out_size * sizeof(float), stream);

  scatter_kernel<<<(kNEnv + 255) / 256, 256, 0, stream>>>(species, sid, cnt, perm, sidp);
  convert_sp_kernel<<<(kNSpecies * kNSupport * kDPS) / (256 * 8), 256, 0, stream>>>(sp, sp_bf);

  dim3 grid(kCap / BN, kNSpecies);  // (512, 4); early-out past count
  gap_gemm_kernel<<<grid, 256, 0, stream>>>(ps, sp_bf, w, cnt, perm, sidp, energy);
}

// Round 6
// 553.506 us; speedup vs baseline: 1.4183x; 1.4183x over previous
//
#include <hip/hip_runtime.h>
#include <hip/hip_bf16.h>

// GapModel: per_row[n] = (1/||ps_n||^2) * sum_m w[s_n,m] * (ps_n . sp[s_n,m])^2
// energy[t] = sum_{n: sid[n]==t} per_row[n]
//
// R6: B-stationary register GEMM. Each wave pins its 32-m x 512-K bf16 B slice
// in 128 VGPRs (loaded once); 8 waves/block cover all 256 m. Blocks stream
// 16-env A tiles: 32 independent b128 loads/tile -> in-register cvt+norm ->
// 32 MFMA into just 2 accumulator frags (8 VGPRs). No LDS staging, no K-loop
// barriers, no dynamic register indexing (R4/R5 spill bug). Per-wave epilogue
// atomics directly (division distributes across m-slices).

constexpr int kNEnv     = 100000;
constexpr int kDPS      = 512;
constexpr int kNSpecies = 4;
constexpr int kNSupport = 256;
constexpr int kCap      = 32768;
constexpr int kBlocksPerSpecies = 128;

typedef __attribute__((ext_vector_type(8))) short short8;
typedef __attribute__((ext_vector_type(4))) float f32x4;

__device__ __forceinline__ short8 pack_bf16x8(const float4& a, const float4& b) {
  union { short8 v; __hip_bfloat162 h[4]; } u;
  u.h[0] = __float22bfloat162_rn({a.x, a.y});
  u.h[1] = __float22bfloat162_rn({a.z, a.w});
  u.h[2] = __float22bfloat162_rn({b.x, b.y});
  u.h[3] = __float22bfloat162_rn({b.z, b.w});
  return u.v;
}

// ---------------- single-pass species bucket scatter ----------------
__global__ void scatter_kernel(const int* __restrict__ species, const int* __restrict__ sid,
                               int* __restrict__ cnt, int* __restrict__ perm,
                               int* __restrict__ sidp) {
  __shared__ int lcnt[kNSpecies];
  __shared__ int lbase[kNSpecies];
  int t = threadIdx.x;
  if (t < kNSpecies) lcnt[t] = 0;
  __syncthreads();
  int i = blockIdx.x * 256 + t;
  bool v = i < kNEnv;
  int s = 0, r = 0, g = 0;
  if (v) { s = species[i]; r = atomicAdd(&lcnt[s], 1); g = sid[i]; }
  __syncthreads();
  if (t < kNSpecies) lbase[t] = lcnt[t] ? atomicAdd(&cnt[t], lcnt[t]) : 0;
  __syncthreads();
  if (v) {
    int d = s * kCap + lbase[s] + r;
    perm[d] = i;
    sidp[d] = g;
  }
}

// ---------------- sp fp32 -> bf16 (2 MB; leaves sp_bf hot in L2) ----------
__global__ __launch_bounds__(256) void convert_sp_kernel(
    const float* __restrict__ sp, short* __restrict__ sp_bf) {
  size_t g = ((size_t)blockIdx.x * 256 + threadIdx.x) * 8;
  float4 x = *(const float4*)(sp + g);
  float4 y = *(const float4*)(sp + g + 4);
  *(short8*)(sp_bf + g) = pack_bf16x8(x, y);
}

// ---------------- B-stationary fused GEMM + norm + epilogue ----------------
// 512 threads = 8 waves; wave wv owns m-slice [wv*32, wv*32+32).
// B frags pinned: Bf[fj][kc], fj in {0,1}, kc in 0..15  (128 VGPRs).
// Per 16-env tile: 32x b128 A loads -> cvt -> 32 MFMA -> epilogue atomics.
__global__ __launch_bounds__(512, 2) void gap_gemm_kernel(
    const float* __restrict__ ps, const short* __restrict__ sp_bf,
    const float* __restrict__ w, const int* __restrict__ cnt,
    const int* __restrict__ perm, const int* __restrict__ sidp,
    float* __restrict__ energy) {
  const int s     = blockIdx.y;
  const int count = min(cnt[s], kCap);
  if (count == 0) return;
  const int nt  = (count + 15) >> 4;                       // 16-env tiles
  const int per = (nt + kBlocksPerSpecies - 1) / kBlocksPerSpecies;
  const int t0  = blockIdx.x * per;
  const int t1  = min(t0 + per, nt);
  if (t0 >= t1) return;

  const int tid  = threadIdx.x;
  const int wv   = tid >> 6;        // 0..7 -> m-slice
  const int lane = tid & 63;
  const int l15  = lane & 15;
  const int lq   = lane >> 4;

  __shared__ float sqw[8][16];

  // ---- load B slice into registers (once) ----
  // B frag: row m = wv*32 + fj*16 + l15 ; k = kc*32 + lq*8 + j
  const short* bbase = sp_bf + ((size_t)s * kNSupport + wv * 32 + l15) * kDPS + lq * 8;
  short8 Bf0[16], Bf1[16];
  #pragma unroll
  for (int kc = 0; kc < 16; ++kc) {
    Bf0[kc] = *(const short8*)(bbase + kc * 32);
    Bf1[kc] = *(const short8*)(bbase + 16 * kDPS + kc * 32);
  }
  const float wgt0 = w[s * kNSupport + wv * 32 + l15];
  const float wgt1 = w[s * kNSupport + wv * 32 + 16 + l15];

  for (int t = t0; t < t1; ++t) {
    // A rows: env row = t*16 + l15 (clamped; tail masked at the atomic)
    int ge = t * 16 + l15;
    int gc = ge < count ? ge : count - 1;
    const float* aptr = ps + (size_t)perm[s * kCap + gc] * kDPS + lq * 8;

    f32x4 acc0 = {0.f, 0.f, 0.f, 0.f};
    f32x4 acc1 = {0.f, 0.f, 0.f, 0.f};
    float sq = 0.f;

    #pragma unroll
    for (int kc = 0; kc < 16; ++kc) {
      float4 x = *(const float4*)(aptr + kc * 32);
      float4 y = *(const float4*)(aptr + kc * 32 + 4);
      sq += x.x * x.x + x.y * x.y + x.z * x.z + x.w * x.w
          + y.x * y.x + y.y * y.y + y.z * y.z + y.w * y.w;
      short8 af = pack_bf16x8(x, y);
      acc0 = __builtin_amdgcn_mfma_f32_16x16x32_bf16(af, Bf0[kc], acc0, 0, 0, 0);
      acc1 = __builtin_amdgcn_mfma_f32_16x16x32_bf16(af, Bf1[kc], acc1, 0, 0, 0);
    }

    // ||ps||^2: lane covers env l15, k-slice lq -> reduce over lq (bits 4,5)
    sq += __shfl_xor(sq, 16, 64);
    sq += __shfl_xor(sq, 32, 64);
    if (lq == 0) sqw[wv][l15] = sq;   // intra-wave LDS, no barrier needed

    // epilogue: C/D col(m)=l15, row(env)=lq*4+r. Per-wave partial, scaled,
    // straight to global atomic (division distributes over m-slices).
    #pragma unroll
    for (int r = 0; r < 4; ++r) {
      float c0 = acc0[r], c1 = acc1[r];
      float p = c0 * c0 * wgt0 + c1 * c1 * wgt1;
      p += __shfl_xor(p, 1, 64);
      p += __shfl_xor(p, 2, 64);
      p += __shfl_xor(p, 4, 64);
      p += __shfl_xor(p, 8, 64);
      if (l15 == 0) {
        int eg = t * 16 + lq * 4 + r;
        if (eg < count) {
          float invn = 1.0f / sqw[wv][lq * 4 + r];
          atomicAdd(&energy[sidp[s * kCap + eg]], p * invn);
        }
      }
    }
  }
}

extern "C" void kernel_launch(void* const* d_in, const int* in_sizes, int n_in,
                              void* d_out, int out_size, void* d_ws, size_t ws_size,
                              hipStream_t stream) {
  const float* ps      = (const float*)d_in[0];
  const float* sp      = (const float*)d_in[1];
  const float* w       = (const float*)d_in[2];
  const int*   species = (const int*)d_in[3];
  const int*   sid     = (const int*)d_in[4];
  float* energy = (float*)d_out;

  char* wsb = (char*)d_ws;
  size_t off = 0;
  int* cnt  = (int*)(wsb + off); off += 256;
  int* perm = (int*)(wsb + off); off += (size_t)kNSpecies * kCap * 4;
  int* sidp = (int*)(wsb + off); off += (size_t)kNSpecies * kCap * 4;
  short* sp_bf = (short*)(wsb + off);

  hipMemsetAsync(cnt, 0, 16, stream);
  hipMemsetAsync(energy, 0, out_size * sizeof(float), stream);

  scatter_kernel<<<(kNEnv + 255) / 256, 256, 0, stream>>>(species, sid, cnt, perm, sidp);
  convert_sp_kernel<<<(kNSpecies * kNSupport * kDPS) / (256 * 8), 256, 0, stream>>>(sp, sp_bf);

  dim3 grid(kBlocksPerSpecies, kNSpecies);  // 512 blocks x 512 threads
  gap_gemm_kernel<<<grid, 512, 0, stream>>>(ps, sp_bf, w, cnt, perm, sidp, energy);
}